// Round 1
// baseline (602.661 us; speedup 1.0000x reference)
//
#include <hip/hip_runtime.h>

#define HEADS 4
#define DH 64
#define NHID 256   // HEADS*DH
#define KIN 256
#define NEG_SLOPE 0.2f

// ---------------- Projection GEMM + attention logits ----------------
// ft[M,256] = feat[M,256] @ W[256,256];  el/er[M,4] = sum_d ft*attn
// BM=128, BN=128, BK=16, 256 threads, 8x8 per-thread register tile.
// LDS layout: chunks of 8 floats padded to 12 -> 2-way max bank aliasing (free).
#define BK 16
#define CH 12      // chunk stride (8 floats + 4 pad)
#define LROW 192   // 16 chunks * CH

__global__ __launch_bounds__(256, 2) void k_proj(
    const float* __restrict__ A, const float* __restrict__ W,
    const float* __restrict__ al, const float* __restrict__ ar,
    float* __restrict__ ft, float* __restrict__ el, float* __restrict__ er, int M)
{
  __shared__ float As[BK * LROW];
  __shared__ float Bs[BK * LROW];
  const int t  = threadIdx.x;
  const int tx = t & 15, ty = t >> 4;
  const int row0 = blockIdx.x * 128;
  const int col0 = blockIdx.y * 128;

  float acc[8][8] = {};

  const int s_row = t >> 1;        // A staging: row 0..127
  const int s_kq  = (t & 1) * 2;   // A staging: float4 index base {0,2}
  const int b_kk  = t >> 4;        // B staging: k 0..15
  const int b_cq  = t & 15;        // B staging: col chunk 0..15

  for (int k0 = 0; k0 < KIN; k0 += BK) {
    // stage A tile (128 rows x 16 k), stored transposed As[k][row-chunked]
    #pragma unroll
    for (int j = 0; j < 2; ++j) {
      int kq = s_kq + j;  // 0..3
      float4 v = make_float4(0.f, 0.f, 0.f, 0.f);
      int grow = row0 + s_row;
      if (grow < M) v = *(const float4*)(A + (size_t)grow * KIN + k0 + kq * 4);
      int basei = (s_row >> 3) * CH + (s_row & 7);
      As[(kq * 4 + 0) * LROW + basei] = v.x;
      As[(kq * 4 + 1) * LROW + basei] = v.y;
      As[(kq * 4 + 2) * LROW + basei] = v.z;
      As[(kq * 4 + 3) * LROW + basei] = v.w;
    }
    // stage B tile (16 k x 128 cols)
    #pragma unroll
    for (int j = 0; j < 2; ++j) {
      float4 v = *(const float4*)(W + (size_t)(k0 + b_kk) * NHID + col0 + b_cq * 8 + j * 4);
      int basei = b_kk * LROW + b_cq * CH + j * 4;
      Bs[basei + 0] = v.x; Bs[basei + 1] = v.y;
      Bs[basei + 2] = v.z; Bs[basei + 3] = v.w;
    }
    __syncthreads();
    #pragma unroll
    for (int kk = 0; kk < BK; ++kk) {
      const float* ap = &As[kk * LROW + ty * CH];
      const float* bp = &Bs[kk * LROW + tx * CH];
      float4 a0 = *(const float4*)(ap);
      float4 a1 = *(const float4*)(ap + 4);
      float4 b0 = *(const float4*)(bp);
      float4 b1 = *(const float4*)(bp + 4);
      float a[8] = {a0.x, a0.y, a0.z, a0.w, a1.x, a1.y, a1.z, a1.w};
      float b[8] = {b0.x, b0.y, b0.z, b0.w, b1.x, b1.y, b1.z, b1.w};
      #pragma unroll
      for (int r = 0; r < 8; ++r)
        #pragma unroll
        for (int c = 0; c < 8; ++c)
          acc[r][c] += a[r] * b[c];
    }
    __syncthreads();
  }

  // write ft
  #pragma unroll
  for (int r = 0; r < 8; ++r) {
    int row = row0 + ty * 8 + r;
    if (row < M) {
      float* p = ft + (size_t)row * NHID + col0 + tx * 8;
      *(float4*)(p)     = make_float4(acc[r][0], acc[r][1], acc[r][2], acc[r][3]);
      *(float4*)(p + 4) = make_float4(acc[r][4], acc[r][5], acc[r][6], acc[r][7]);
    }
  }

  // el/er epilogue: block covers 2 heads (64 cols each); head_local = tx>>3
  float4 al0 = *(const float4*)(al + col0 + tx * 8);
  float4 al1 = *(const float4*)(al + col0 + tx * 8 + 4);
  float4 ar0 = *(const float4*)(ar + col0 + tx * 8);
  float4 ar1 = *(const float4*)(ar + col0 + tx * 8 + 4);
  float alv[8] = {al0.x, al0.y, al0.z, al0.w, al1.x, al1.y, al1.z, al1.w};
  float arv[8] = {ar0.x, ar0.y, ar0.z, ar0.w, ar1.x, ar1.y, ar1.z, ar1.w};
  int h = (col0 >> 6) + (tx >> 3);  // global head index
  #pragma unroll
  for (int r = 0; r < 8; ++r) {
    float pl = 0.f, pr = 0.f;
    #pragma unroll
    for (int c = 0; c < 8; ++c) { pl += acc[r][c] * alv[c]; pr += acc[r][c] * arv[c]; }
    pl += __shfl_xor(pl, 1); pl += __shfl_xor(pl, 2); pl += __shfl_xor(pl, 4);
    pr += __shfl_xor(pr, 1); pr += __shfl_xor(pr, 2); pr += __shfl_xor(pr, 4);
    if ((tx & 7) == 0) {
      int row = row0 + ty * 8 + r;
      if (row < M) { el[row * HEADS + h] = pl; er[row * HEADS + h] = pr; }
    }
  }
}

// ---------------- CSR build ----------------
__global__ void k_deg(const int* __restrict__ dst, int* __restrict__ deg, int E) {
  int e = blockIdx.x * 256 + threadIdx.x;
  if (e < E) atomicAdd(&deg[dst[e]], 1);
}

__global__ __launch_bounds__(1024) void k_scan1(const int* __restrict__ deg,
                                                int* __restrict__ offs,
                                                int* __restrict__ part, int N) {
  __shared__ int s[1024];
  int tid = threadIdx.x;
  int idx = blockIdx.x * 1024 + tid;
  int v = (idx < N) ? deg[idx] : 0;
  s[tid] = v;
  __syncthreads();
  for (int off = 1; off < 1024; off <<= 1) {
    int tmp = (tid >= off) ? s[tid - off] : 0;
    __syncthreads();
    s[tid] += tmp;
    __syncthreads();
  }
  if (idx < N) offs[idx] = s[tid] - v;  // local exclusive
  if (tid == 1023) part[blockIdx.x] = s[1023];
}

__global__ __launch_bounds__(128) void k_scan2(const int* __restrict__ part,
                                               int* __restrict__ pbase, int nb) {
  __shared__ int s[128];
  int tid = threadIdx.x;
  int v = (tid < nb) ? part[tid] : 0;
  s[tid] = v;
  __syncthreads();
  for (int off = 1; off < 128; off <<= 1) {
    int tmp = (tid >= off) ? s[tid - off] : 0;
    __syncthreads();
    s[tid] += tmp;
    __syncthreads();
  }
  if (tid < nb) pbase[tid] = s[tid] - v;
}

__global__ void k_scan3(int* __restrict__ offs, const int* __restrict__ pbase,
                        int N, int E) {
  int idx = blockIdx.x * 256 + threadIdx.x;
  if (idx < N) offs[idx] += pbase[idx >> 10];
  if (idx == N) offs[N] = E;
}

__global__ void k_fill(const int* __restrict__ src, const int* __restrict__ dst,
                       const int* __restrict__ offs, int* __restrict__ cursor,
                       int* __restrict__ csr, int E) {
  int e = blockIdx.x * 256 + threadIdx.x;
  if (e < E) {
    int d = dst[e];
    int p = atomicAdd(&cursor[d], 1);
    csr[offs[d] + p] = src[e];
  }
}

// ---------------- Aggregation: one wave per dst node ----------------
// rst[n] = (sum_e ex_e * ft[src_e]) / (sum_e ex_e),  ex = exp(leakyrelu(el[src]+er[n]))
__global__ __launch_bounds__(256) void k_aggr(
    const float* __restrict__ ft, const float* __restrict__ el,
    const float* __restrict__ er, const int* __restrict__ offs,
    const int* __restrict__ csr, float* __restrict__ out, int N)
{
  int n = blockIdx.x * 4 + (threadIdx.x >> 6);
  int lane = threadIdx.x & 63;
  if (n >= N) return;
  int head = lane >> 4;                       // lane's float4 lives in this head
  float erh = er[n * HEADS + head];
  int start = offs[n], end = offs[n + 1];
  const float4* ft4 = (const float4*)ft;
  float4 acc = make_float4(0.f, 0.f, 0.f, 0.f);
  float ws = 0.f;
  for (int e = start; e < end; ++e) {
    int s = csr[e];
    float x = el[s * HEADS + head] + erh;
    x = x > 0.f ? x : NEG_SLOPE * x;
    float ex = __expf(x);
    ws += ex;
    float4 f = ft4[s * (NHID / 4) + lane];
    acc.x += ex * f.x; acc.y += ex * f.y; acc.z += ex * f.z; acc.w += ex * f.w;
  }
  float inv = (end > start) ? 1.f / ws : 0.f;
  float4 o = make_float4(acc.x * inv, acc.y * inv, acc.z * inv, acc.w * inv);
  ((float4*)out)[(size_t)n * (NHID / 4) + lane] = o;
}

// ---------------- launch ----------------
extern "C" void kernel_launch(void* const* d_in, const int* in_sizes, int n_in,
                              void* d_out, int out_size, void* d_ws, size_t ws_size,
                              hipStream_t stream)
{
  const float* feat = (const float*)d_in[0];
  const float* W    = (const float*)d_in[1];
  const float* al   = (const float*)d_in[2];
  const float* ar   = (const float*)d_in[3];
  const int*   src  = (const int*)d_in[4];
  const int*   dst  = (const int*)d_in[5];
  const int M = in_sizes[0] / KIN;   // 100000
  const int E = in_sizes[4];         // 1600000
  float* out = (float*)d_out;

  char* base = (char*)d_ws;
  size_t off = 0;
  auto alloc = [&](size_t b) { char* p = base + off; off = (off + b + 255) & ~(size_t)255; return p; };
  float* ft     = (float*)alloc((size_t)M * NHID * sizeof(float));   // 102.4 MB
  float* el     = (float*)alloc((size_t)M * HEADS * sizeof(float));
  float* er     = (float*)alloc((size_t)M * HEADS * sizeof(float));
  int*   deg    = (int*)alloc((size_t)M * sizeof(int));
  int*   offs   = (int*)alloc((size_t)(M + 1) * sizeof(int));
  int*   cursor = (int*)alloc((size_t)M * sizeof(int));
  int*   part   = (int*)alloc(1024 * sizeof(int));
  int*   pbase  = (int*)alloc(1024 * sizeof(int));
  int*   csr    = (int*)alloc((size_t)E * sizeof(int));
  (void)ws_size; (void)n_in; (void)out_size;

  hipMemsetAsync(deg, 0, (size_t)M * sizeof(int), stream);
  hipMemsetAsync(cursor, 0, (size_t)M * sizeof(int), stream);

  dim3 gp((M + 127) / 128, NHID / 128);
  k_proj<<<gp, 256, 0, stream>>>(feat, W, al, ar, ft, el, er, M);
  k_deg<<<(E + 255) / 256, 256, 0, stream>>>(dst, deg, E);
  int nb = (M + 1023) / 1024;                 // 98 (must be <= 128)
  k_scan1<<<nb, 1024, 0, stream>>>(deg, offs, part, M);
  k_scan2<<<1, 128, 0, stream>>>(part, pbase, nb);
  k_scan3<<<(M + 1 + 255) / 256, 256, 0, stream>>>(offs, pbase, M, E);
  k_fill<<<(E + 255) / 256, 256, 0, stream>>>(src, dst, offs, cursor, csr, E);
  k_aggr<<<(M + 3) / 4, 256, 0, stream>>>(ft, el, er, offs, csr, out, M);
}

// Round 2
// 446.698 us; speedup vs baseline: 1.3491x; 1.3491x over previous
//
#include <hip/hip_runtime.h>

#define HEADS 4
#define DH 64
#define NHID 256   // HEADS*DH
#define KIN 256
#define NEG_SLOPE 0.2f

typedef __attribute__((ext_vector_type(8))) short short8;
typedef __attribute__((ext_vector_type(4))) float f32x4;

__device__ inline float bf2f(unsigned short u) {
  union { unsigned int i; float f; } v; v.i = ((unsigned int)u) << 16; return v.f;
}
__device__ inline unsigned short f2bf(float f) {
  union { float f; unsigned int i; } v; v.f = f;
  unsigned int r = v.i + 0x7FFF + ((v.i >> 16) & 1);  // RNE
  return (unsigned short)(r >> 16);
}

// -------- k_prep: fold attention vectors into W:  Wal[h][k] = sum_d W[k][h*64+d]*al[h][d]
__global__ void k_prep(const float* __restrict__ W, const float* __restrict__ al,
                       const float* __restrict__ ar,
                       float* __restrict__ WalT, float* __restrict__ WarT) {
  int k = threadIdx.x;  // 256
  #pragma unroll
  for (int h = 0; h < HEADS; ++h) {
    float sl = 0.f, sr = 0.f;
    for (int d = 0; d < DH; ++d) {
      float w = W[k * NHID + h * DH + d];
      sl += w * al[h * DH + d];
      sr += w * ar[h * DH + d];
    }
    WalT[h * 256 + k] = sl;
    WarT[h * 256 + k] = sr;
  }
}

// -------- k_cvtW: W[k][n] fp32 -> Wt[n][k] bf16 (transpose+convert, tiny)
__global__ void k_cvtW(const float* __restrict__ W, unsigned short* __restrict__ Wt) {
  int n = blockIdx.x, k = threadIdx.x;
  Wt[n * 256 + k] = f2bf(W[k * 256 + n]);
}

// -------- k_cvt: feat fp32 -> Abf bf16; el/er computed EXACT in fp32 via Wal/War.
// One wave per row: lane holds float4 at col lane*4.
__global__ __launch_bounds__(256) void k_cvt(
    const float* __restrict__ feat, const float* __restrict__ WalT,
    const float* __restrict__ WarT, unsigned short* __restrict__ Abf,
    float* __restrict__ el, float* __restrict__ er, int M)
{
  int row = blockIdx.x * 4 + (threadIdx.x >> 6);
  int lane = threadIdx.x & 63;
  if (row >= M) return;
  // hoistable weights: per lane, 4 k-values x 4 heads
  float4 wl[4], wr[4];
  #pragma unroll
  for (int h = 0; h < 4; ++h) {
    wl[h] = *(const float4*)(WalT + h * 256 + lane * 4);
    wr[h] = *(const float4*)(WarT + h * 256 + lane * 4);
  }
  float4 v = ((const float4*)feat)[(size_t)row * 64 + lane];
  ushort4 o;
  o.x = f2bf(v.x); o.y = f2bf(v.y); o.z = f2bf(v.z); o.w = f2bf(v.w);
  ((ushort4*)Abf)[(size_t)row * 64 + lane] = o;
  float pl[4], pr[4];
  #pragma unroll
  for (int h = 0; h < 4; ++h) {
    pl[h] = v.x * wl[h].x + v.y * wl[h].y + v.z * wl[h].z + v.w * wl[h].w;
    pr[h] = v.x * wr[h].x + v.y * wr[h].y + v.z * wr[h].z + v.w * wr[h].w;
  }
  #pragma unroll
  for (int s = 1; s < 64; s <<= 1) {
    #pragma unroll
    for (int h = 0; h < 4; ++h) {
      pl[h] += __shfl_xor(pl[h], s);
      pr[h] += __shfl_xor(pr[h], s);
    }
  }
  if (lane == 0) {
    #pragma unroll
    for (int h = 0; h < 4; ++h) {
      el[row * HEADS + h] = pl[h];
      er[row * HEADS + h] = pr[h];
    }
  }
}

// -------- k_gemm: ftb[M][256] bf16 = Abf[M][256] @ Wt[256][256]^T  (both row-major [.,K])
// m97 structure: 128x128 tile, BK=32, 4 waves, global_load_lds w=16, XOR chunk swizzle.
__global__ __launch_bounds__(256, 2) void k_gemm(
    const unsigned short* __restrict__ A, const unsigned short* __restrict__ Bt,
    unsigned short* __restrict__ ftb, int M)
{
  __shared__ unsigned short As[128 * 32];
  __shared__ unsigned short Bs[128 * 32];
  const int t = threadIdx.x;
  const int lane = t & 63;
  const int w = t >> 6;
  const int wr = w >> 1, wc = w & 1;
  const int row0 = blockIdx.x * 128;
  const int col0 = blockIdx.y * 128;

  f32x4 acc[4][4] = {};

  // staging geometry: lds byte o = w*2048 + j*1024 + lane*16; row=o>>6, chunk=(o>>4)&3
  int soff[2], srow[2], skc[2];
  #pragma unroll
  for (int j = 0; j < 2; ++j) {
    int o = w * 2048 + j * 1024 + lane * 16;
    int r = o >> 6, c = (o >> 4) & 3;
    soff[j] = o; srow[j] = r; skc[j] = c ^ ((r >> 1) & 3);
  }
  int arow[2];
  #pragma unroll
  for (int j = 0; j < 2; ++j) {
    int r = row0 + srow[j];
    arow[j] = r < M ? r : M - 1;
  }

  for (int k0 = 0; k0 < KIN; k0 += 32) {
    #pragma unroll
    for (int j = 0; j < 2; ++j) {
      const unsigned short* ga = A + (size_t)arow[j] * KIN + k0 + skc[j] * 8;
      __builtin_amdgcn_global_load_lds(
          (const __attribute__((address_space(1))) void*)ga,
          (__attribute__((address_space(3))) void*)((char*)As + soff[j]), 16, 0, 0);
      const unsigned short* gb = Bt + (size_t)(col0 + srow[j]) * KIN + k0 + skc[j] * 8;
      __builtin_amdgcn_global_load_lds(
          (const __attribute__((address_space(1))) void*)gb,
          (__attribute__((address_space(3))) void*)((char*)Bs + soff[j]), 16, 0, 0);
    }
    __syncthreads();
    const int i = lane & 15, kcq = lane >> 4;
    short8 af[4], bf[4];
    #pragma unroll
    for (int m = 0; m < 4; ++m) {
      int r = wr * 64 + m * 16 + i;
      int c = kcq ^ ((r >> 1) & 3);
      af[m] = *(const short8*)((const char*)As + r * 64 + c * 16);
    }
    #pragma unroll
    for (int n = 0; n < 4; ++n) {
      int r = wc * 64 + n * 16 + i;
      int c = kcq ^ ((r >> 1) & 3);
      bf[n] = *(const short8*)((const char*)Bs + r * 64 + c * 16);
    }
    #pragma unroll
    for (int m = 0; m < 4; ++m)
      #pragma unroll
      for (int n = 0; n < 4; ++n)
        acc[m][n] = __builtin_amdgcn_mfma_f32_16x16x32_bf16(af[m], bf[n], acc[m][n], 0, 0, 0);
    __syncthreads();
  }

  // C/D layout: col = lane&15, row = (lane>>4)*4 + reg  [m89-verified]
  const int ci = lane & 15, rg = lane >> 4;
  const int gc = col0 + wc * 64;
  #pragma unroll
  for (int m = 0; m < 4; ++m) {
    #pragma unroll
    for (int r = 0; r < 4; ++r) {
      int row = row0 + wr * 64 + m * 16 + rg * 4 + r;
      if (row < M) {
        unsigned short* fp = ftb + (size_t)row * NHID + gc;
        #pragma unroll
        for (int n = 0; n < 4; ++n) fp[n * 16 + ci] = f2bf(acc[m][n][r]);
      }
    }
  }
}

// ---------------- CSR build ----------------
__global__ void k_deg(const int* __restrict__ dst, int* __restrict__ deg, int E) {
  int e = blockIdx.x * 256 + threadIdx.x;
  if (e < E) atomicAdd(&deg[dst[e]], 1);
}

__global__ __launch_bounds__(1024) void k_scan1(const int* __restrict__ deg,
                                                int* __restrict__ offs,
                                                int* __restrict__ part, int N) {
  __shared__ int s[1024];
  int tid = threadIdx.x;
  int idx = blockIdx.x * 1024 + tid;
  int v = (idx < N) ? deg[idx] : 0;
  s[tid] = v;
  __syncthreads();
  for (int off = 1; off < 1024; off <<= 1) {
    int tmp = (tid >= off) ? s[tid - off] : 0;
    __syncthreads();
    s[tid] += tmp;
    __syncthreads();
  }
  if (idx < N) offs[idx] = s[tid] - v;
  if (tid == 1023) part[blockIdx.x] = s[1023];
}

__global__ __launch_bounds__(128) void k_scan2(const int* __restrict__ part,
                                               int* __restrict__ pbase, int nb) {
  __shared__ int s[128];
  int tid = threadIdx.x;
  int v = (tid < nb) ? part[tid] : 0;
  s[tid] = v;
  __syncthreads();
  for (int off = 1; off < 128; off <<= 1) {
    int tmp = (tid >= off) ? s[tid - off] : 0;
    __syncthreads();
    s[tid] += tmp;
    __syncthreads();
  }
  if (tid < nb) pbase[tid] = s[tid] - v;
}

__global__ void k_scan3(int* __restrict__ offs, const int* __restrict__ pbase,
                        int N, int E) {
  int idx = blockIdx.x * 256 + threadIdx.x;
  if (idx < N) offs[idx] += pbase[idx >> 10];
  if (idx == N) offs[N] = E;
}

__global__ void k_fill(const int* __restrict__ src, const int* __restrict__ dst,
                       const int* __restrict__ offs, int* __restrict__ cursor,
                       int* __restrict__ csr, int E) {
  int e = blockIdx.x * 256 + threadIdx.x;
  if (e < E) {
    int d = dst[e];
    int p = atomicAdd(&cursor[d], 1);
    csr[offs[d] + p] = src[e];
  }
}

// ---------------- Aggregation: one wave per dst node, bf16 ft gather ----------------
__global__ __launch_bounds__(256) void k_aggr(
    const unsigned short* __restrict__ ftb, const float* __restrict__ el,
    const float* __restrict__ er, const int* __restrict__ offs,
    const int* __restrict__ csr, float* __restrict__ out, int N)
{
  int n = blockIdx.x * 4 + (threadIdx.x >> 6);
  int lane = threadIdx.x & 63;
  if (n >= N) return;
  int head = lane >> 4;
  float erh = er[n * HEADS + head];
  int start = offs[n], end = offs[n + 1];
  const ushort4* ft4 = (const ushort4*)ftb;
  float4 acc = make_float4(0.f, 0.f, 0.f, 0.f);
  float ws = 0.f;
  for (int e = start; e < end; ++e) {
    int s = csr[e];
    float x = el[s * HEADS + head] + erh;
    x = x > 0.f ? x : NEG_SLOPE * x;
    float ex = __expf(x);
    ws += ex;
    ushort4 f = ft4[(size_t)s * 64 + lane];
    acc.x += ex * bf2f(f.x); acc.y += ex * bf2f(f.y);
    acc.z += ex * bf2f(f.z); acc.w += ex * bf2f(f.w);
  }
  float inv = (end > start) ? 1.f / ws : 0.f;
  ((float4*)out)[(size_t)n * 64 + lane] =
      make_float4(acc.x * inv, acc.y * inv, acc.z * inv, acc.w * inv);
}

// ---------------- launch ----------------
extern "C" void kernel_launch(void* const* d_in, const int* in_sizes, int n_in,
                              void* d_out, int out_size, void* d_ws, size_t ws_size,
                              hipStream_t stream)
{
  const float* feat = (const float*)d_in[0];
  const float* W    = (const float*)d_in[1];
  const float* al   = (const float*)d_in[2];
  const float* ar   = (const float*)d_in[3];
  const int*   src  = (const int*)d_in[4];
  const int*   dst  = (const int*)d_in[5];
  const int M = in_sizes[0] / KIN;   // 100000
  const int E = in_sizes[4];         // 1600000
  float* out = (float*)d_out;

  char* base = (char*)d_ws;
  size_t off = 0;
  auto alloc = [&](size_t b) { char* p = base + off; off = (off + b + 255) & ~(size_t)255; return p; };
  unsigned short* Abf  = (unsigned short*)alloc((size_t)M * NHID * sizeof(unsigned short)); // 51.2 MB
  unsigned short* ftb  = (unsigned short*)alloc((size_t)M * NHID * sizeof(unsigned short)); // 51.2 MB
  unsigned short* Wt   = (unsigned short*)alloc(256 * 256 * sizeof(unsigned short));
  float* WalT   = (float*)alloc(4 * 256 * sizeof(float));
  float* WarT   = (float*)alloc(4 * 256 * sizeof(float));
  float* el     = (float*)alloc((size_t)M * HEADS * sizeof(float));
  float* er     = (float*)alloc((size_t)M * HEADS * sizeof(float));
  int*   deg    = (int*)alloc((size_t)M * sizeof(int));
  int*   offs   = (int*)alloc((size_t)(M + 1) * sizeof(int));
  int*   cursor = (int*)alloc((size_t)M * sizeof(int));
  int*   part   = (int*)alloc(1024 * sizeof(int));
  int*   pbase  = (int*)alloc(1024 * sizeof(int));
  int*   csr    = (int*)alloc((size_t)E * sizeof(int));
  (void)ws_size; (void)n_in; (void)out_size;

  hipMemsetAsync(deg, 0, (size_t)M * sizeof(int), stream);
  hipMemsetAsync(cursor, 0, (size_t)M * sizeof(int), stream);

  k_prep<<<1, 256, 0, stream>>>(W, al, ar, WalT, WarT);
  k_cvtW<<<256, 256, 0, stream>>>(W, Wt);
  k_cvt<<<(M + 3) / 4, 256, 0, stream>>>(feat, WalT, WarT, Abf, el, er, M);
  dim3 gg((M + 127) / 128, NHID / 128);
  k_gemm<<<gg, 256, 0, stream>>>(Abf, Wt, ftb, M);
  k_deg<<<(E + 255) / 256, 256, 0, stream>>>(dst, deg, E);
  int nb = (M + 1023) / 1024;
  k_scan1<<<nb, 1024, 0, stream>>>(deg, offs, part, M);
  k_scan2<<<1, 128, 0, stream>>>(part, pbase, nb);
  k_scan3<<<(M + 1 + 255) / 256, 256, 0, stream>>>(offs, pbase, M, E);
  k_fill<<<(E + 255) / 256, 256, 0, stream>>>(src, dst, offs, cursor, csr, E);
  k_aggr<<<(M + 3) / 4, 256, 0, stream>>>(ftb, el, er, offs, csr, out, M);
}

// Round 3
// 381.463 us; speedup vs baseline: 1.5799x; 1.1710x over previous
//
#include <hip/hip_runtime.h>

#define HEADS 4
#define DH 64
#define NHID 256   // HEADS*DH
#define KIN 256
#define NEG_SLOPE 0.2f

typedef __attribute__((ext_vector_type(8))) short short8;
typedef __attribute__((ext_vector_type(4))) float f32x4;

__device__ inline float bf2f(unsigned short u) {
  union { unsigned int i; float f; } v; v.i = ((unsigned int)u) << 16; return v.f;
}
__device__ inline unsigned short f2bf(float f) {
  union { float f; unsigned int i; } v; v.f = f;
  unsigned int r = v.i + 0x7FFF + ((v.i >> 16) & 1);  // RNE
  return (unsigned short)(r >> 16);
}

// -------- k_cvtW: W[k][n] fp32 -> Wt[n][k] bf16 (transpose+convert, tiny)
__global__ void k_cvtW(const float* __restrict__ W, unsigned short* __restrict__ Wt) {
  int n = blockIdx.x, k = threadIdx.x;
  Wt[n * 256 + k] = f2bf(W[k * 256 + n]);
}

// -------- k_gemm: fused projection + logits.
// ftb[M][256] bf16 = bf16(feat) @ Wt^T;  el/er[M][4] from fp32 accumulator.
// BM=64, BN=256 (wave w == head w), BK=32, 4 waves.
// A reg-staged from fp32 with convert; B via global_load_lds w=16 (pre-swizzled src).
__global__ __launch_bounds__(256, 2) void k_gemm(
    const float* __restrict__ feat, const unsigned short* __restrict__ Wt,
    const float* __restrict__ al, const float* __restrict__ ar,
    unsigned short* __restrict__ ftb, float* __restrict__ el,
    float* __restrict__ er, int M)
{
  __shared__ unsigned short As[64 * 32];    // 4 KB
  __shared__ unsigned short Bs[256 * 32];   // 16 KB
  const int t = threadIdx.x;
  const int lane = t & 63;
  const int w = t >> 6;                 // wave index == head == col-block
  const int row0 = blockIdx.x * 64;

  f32x4 acc[4][4] = {};

  // A staging geometry: thread t -> row ra, k-chunk ca (8 bf16 per chunk)
  const int ra = t >> 2, ca = t & 3;
  const int arow = min(row0 + ra, M - 1);
  const int adst = ra * 64 + (ca ^ ((ra >> 1) & 3)) * 16;   // swizzled LDS byte

  for (int k0 = 0; k0 < KIN; k0 += 32) {
    // A: 32B fp32 load -> 8 bf16 -> ds_write_b128 (swizzled dest, per-lane ok)
    const float* ga = feat + (size_t)arow * KIN + k0 + ca * 8;
    float4 v0 = *(const float4*)ga;
    float4 v1 = *(const float4*)(ga + 4);
    short8 pk;
    pk[0] = (short)f2bf(v0.x); pk[1] = (short)f2bf(v0.y);
    pk[2] = (short)f2bf(v0.z); pk[3] = (short)f2bf(v0.w);
    pk[4] = (short)f2bf(v1.x); pk[5] = (short)f2bf(v1.y);
    pk[6] = (short)f2bf(v1.z); pk[7] = (short)f2bf(v1.w);
    *(short8*)((char*)As + adst) = pk;
    // B: 16 KB tile via 4x global_load_lds (linear LDS dest, swizzled global src)
    #pragma unroll
    for (int j = 0; j < 4; ++j) {
      int n = j * 64 + (t >> 2);
      int c = t & 3;
      const unsigned short* gb = Wt + n * 256 + k0 + ((c ^ ((n >> 1) & 3)) * 8);
      __builtin_amdgcn_global_load_lds(
          (const __attribute__((address_space(1))) void*)gb,
          (__attribute__((address_space(3))) void*)((char*)Bs + j * 4096 + t * 16),
          16, 0, 0);
    }
    __syncthreads();
    const int i = lane & 15, kc = lane >> 4;
    short8 af[4], bf[4];
    #pragma unroll
    for (int m = 0; m < 4; ++m) {
      int r = m * 16 + i;
      af[m] = *(const short8*)((const char*)As + r * 64 + ((kc ^ ((r >> 1) & 3)) * 16));
    }
    #pragma unroll
    for (int n = 0; n < 4; ++n) {
      int nr = w * 64 + n * 16 + i;
      bf[n] = *(const short8*)((const char*)Bs + nr * 64 + ((kc ^ ((nr >> 1) & 3)) * 16));
    }
    #pragma unroll
    for (int m = 0; m < 4; ++m)
      #pragma unroll
      for (int n = 0; n < 4; ++n)
        acc[m][n] = __builtin_amdgcn_mfma_f32_16x16x32_bf16(af[m], bf[n], acc[m][n], 0, 0, 0);
    __syncthreads();
  }

  // epilogue: C/D layout col=lane&15, row=(lane>>4)*4+reg  [m89-verified]
  const int ci = lane & 15, rg = lane >> 4;
  #pragma unroll
  for (int m = 0; m < 4; ++m) {
    #pragma unroll
    for (int r = 0; r < 4; ++r) {
      int grow = row0 + m * 16 + rg * 4 + r;
      if (grow < M) {
        unsigned short* fp = ftb + (size_t)grow * NHID + w * 64;
        #pragma unroll
        for (int n = 0; n < 4; ++n) fp[n * 16 + ci] = f2bf(acc[m][n][r]);
      }
    }
  }
  // el/er: wave w == head w; row-sum over 64 cols = per-lane 4 + shfl over ci
  float alv[4], arv[4];
  #pragma unroll
  for (int n = 0; n < 4; ++n) {
    alv[n] = al[w * DH + n * 16 + ci];
    arv[n] = ar[w * DH + n * 16 + ci];
  }
  #pragma unroll
  for (int m = 0; m < 4; ++m) {
    #pragma unroll
    for (int r = 0; r < 4; ++r) {
      float pl = 0.f, pr = 0.f;
      #pragma unroll
      for (int n = 0; n < 4; ++n) {
        pl += acc[m][n][r] * alv[n];
        pr += acc[m][n][r] * arv[n];
      }
      pl += __shfl_xor(pl, 1); pl += __shfl_xor(pl, 2);
      pl += __shfl_xor(pl, 4); pl += __shfl_xor(pl, 8);
      pr += __shfl_xor(pr, 1); pr += __shfl_xor(pr, 2);
      pr += __shfl_xor(pr, 4); pr += __shfl_xor(pr, 8);
      if (ci == 0) {
        int grow = row0 + m * 16 + rg * 4 + r;
        if (grow < M) { el[grow * HEADS + w] = pl; er[grow * HEADS + w] = pr; }
      }
    }
  }
}

// ---------------- CSR build ----------------
__global__ void k_deg(const int* __restrict__ dst, int* __restrict__ deg, int E) {
  int e = blockIdx.x * 256 + threadIdx.x;
  if (e < E) atomicAdd(&deg[dst[e]], 1);
}

__global__ __launch_bounds__(1024) void k_scan1(const int* __restrict__ deg,
                                                int* __restrict__ offs,
                                                int* __restrict__ part, int N) {
  __shared__ int s[1024];
  int tid = threadIdx.x;
  int idx = blockIdx.x * 1024 + tid;
  int v = (idx < N) ? deg[idx] : 0;
  s[tid] = v;
  __syncthreads();
  for (int off = 1; off < 1024; off <<= 1) {
    int tmp = (tid >= off) ? s[tid - off] : 0;
    __syncthreads();
    s[tid] += tmp;
    __syncthreads();
  }
  if (idx < N) offs[idx] = s[tid] - v;
  if (tid == 1023) part[blockIdx.x] = s[1023];
}

__global__ __launch_bounds__(128) void k_scan2(const int* __restrict__ part,
                                               int* __restrict__ pbase, int nb) {
  __shared__ int s[128];
  int tid = threadIdx.x;
  int v = (tid < nb) ? part[tid] : 0;
  s[tid] = v;
  __syncthreads();
  for (int off = 1; off < 128; off <<= 1) {
    int tmp = (tid >= off) ? s[tid - off] : 0;
    __syncthreads();
    s[tid] += tmp;
    __syncthreads();
  }
  if (tid < nb) pbase[tid] = s[tid] - v;
}

__global__ void k_scan3(int* __restrict__ offs, const int* __restrict__ pbase,
                        int N, int E) {
  int idx = blockIdx.x * 256 + threadIdx.x;
  if (idx < N) offs[idx] += pbase[idx >> 10];
  if (idx == N) offs[N] = E;
}

// -------- k_fill: scatter src into CSR slot AND precompute per-edge softmax weights
__global__ void k_fill(const int* __restrict__ src, const int* __restrict__ dst,
                       const int* __restrict__ offs, int* __restrict__ cursor,
                       const float* __restrict__ el, const float* __restrict__ er,
                       int* __restrict__ csr, float* __restrict__ ex4, int E) {
  int e = blockIdx.x * 256 + threadIdx.x;
  if (e >= E) return;
  int s = src[e], d = dst[e];
  int p = atomicAdd(&cursor[d], 1);
  int pos = offs[d] + p;
  csr[pos] = s;
  float4 l = *(const float4*)(el + (size_t)s * 4);
  float4 r = *(const float4*)(er + (size_t)d * 4);
  float4 x;
  x.x = l.x + r.x; x.y = l.y + r.y; x.z = l.z + r.z; x.w = l.w + r.w;
  x.x = x.x > 0.f ? x.x : NEG_SLOPE * x.x;
  x.y = x.y > 0.f ? x.y : NEG_SLOPE * x.y;
  x.z = x.z > 0.f ? x.z : NEG_SLOPE * x.z;
  x.w = x.w > 0.f ? x.w : NEG_SLOPE * x.w;
  x.x = __expf(x.x); x.y = __expf(x.y); x.z = __expf(x.z); x.w = __expf(x.w);
  *(float4*)(ex4 + (size_t)pos * 4) = x;
}

// ---------------- Aggregation: one wave per dst node, half-wave per edge ----------------
// lanes 0-31 even edges, 32-63 odd edges; each lane owns 8 dims (ushort8 = 16B load).
__global__ __launch_bounds__(256) void k_aggr(
    const unsigned short* __restrict__ ftb, const float* __restrict__ ex4,
    const int* __restrict__ offs, const int* __restrict__ csr,
    float* __restrict__ out, int N)
{
  int n = blockIdx.x * 4 + (threadIdx.x >> 6);
  int lane = threadIdx.x & 63;
  if (n >= N) return;
  int hl = lane & 31;          // position within half-wave: dims hl*8..hl*8+8
  int half = lane >> 5;
  int hh = hl >> 3;            // head of my 8 dims
  int start = offs[n], end = offs[n + 1];
  const short8* ft8 = (const short8*)ftb;
  float acc[8] = {};
  float ws = 0.f;
  #pragma unroll 2
  for (int e0 = start; e0 < end; e0 += 2) {
    int e = e0 + half;
    bool v = e < end;
    int ec = v ? e : end - 1;
    int s = csr[ec];
    float wgt = v ? ex4[(size_t)ec * 4 + hh] : 0.f;
    short8 f = ft8[(size_t)s * 32 + hl];
    ws += wgt;
    #pragma unroll
    for (int j = 0; j < 8; ++j) acc[j] += wgt * bf2f((unsigned short)f[j]);
  }
  ws += __shfl_xor(ws, 32);
  #pragma unroll
  for (int j = 0; j < 8; ++j) acc[j] += __shfl_xor(acc[j], 32);
  if (half == 0) {
    float inv = (end > start) ? 1.f / ws : 0.f;
    float4* op = (float4*)(out + (size_t)n * NHID + hl * 8);
    op[0] = make_float4(acc[0] * inv, acc[1] * inv, acc[2] * inv, acc[3] * inv);
    op[1] = make_float4(acc[4] * inv, acc[5] * inv, acc[6] * inv, acc[7] * inv);
  }
}

// ---------------- launch ----------------
extern "C" void kernel_launch(void* const* d_in, const int* in_sizes, int n_in,
                              void* d_out, int out_size, void* d_ws, size_t ws_size,
                              hipStream_t stream)
{
  const float* feat = (const float*)d_in[0];
  const float* W    = (const float*)d_in[1];
  const float* al   = (const float*)d_in[2];
  const float* ar   = (const float*)d_in[3];
  const int*   src  = (const int*)d_in[4];
  const int*   dst  = (const int*)d_in[5];
  const int M = in_sizes[0] / KIN;   // 100000
  const int E = in_sizes[4];         // 1600000
  float* out = (float*)d_out;

  char* base = (char*)d_ws;
  size_t off = 0;
  auto alloc = [&](size_t b) { char* p = base + off; off = (off + b + 255) & ~(size_t)255; return p; };
  unsigned short* ftb = (unsigned short*)alloc((size_t)M * NHID * sizeof(unsigned short)); // 51.2 MB
  unsigned short* Wt  = (unsigned short*)alloc(256 * 256 * sizeof(unsigned short));
  float* el     = (float*)alloc((size_t)M * HEADS * sizeof(float));
  float* er     = (float*)alloc((size_t)M * HEADS * sizeof(float));
  float* ex4    = (float*)alloc((size_t)E * HEADS * sizeof(float));   // 25.6 MB
  int*   deg    = (int*)alloc((size_t)M * sizeof(int));
  int*   offs   = (int*)alloc((size_t)(M + 1) * sizeof(int));
  int*   cursor = (int*)alloc((size_t)M * sizeof(int));
  int*   part   = (int*)alloc(1024 * sizeof(int));
  int*   pbase  = (int*)alloc(1024 * sizeof(int));
  int*   csr    = (int*)alloc((size_t)E * sizeof(int));
  (void)ws_size; (void)n_in; (void)out_size;

  hipMemsetAsync(deg, 0, (size_t)M * sizeof(int), stream);
  hipMemsetAsync(cursor, 0, (size_t)M * sizeof(int), stream);

  k_cvtW<<<256, 256, 0, stream>>>(W, Wt);
  k_deg<<<(E + 255) / 256, 256, 0, stream>>>(dst, deg, E);
  int nb = (M + 1023) / 1024;
  k_scan1<<<nb, 1024, 0, stream>>>(deg, offs, part, M);
  k_scan2<<<1, 128, 0, stream>>>(part, pbase, nb);
  k_scan3<<<(M + 1 + 255) / 256, 256, 0, stream>>>(offs, pbase, M, E);
  k_gemm<<<(M + 63) / 64, 256, 0, stream>>>(feat, Wt, al, ar, ftb, el, er, M);
  k_fill<<<(E + 255) / 256, 256, 0, stream>>>(src, dst, offs, cursor, el, er, csr, ex4, E);
  k_aggr<<<(M + 3) / 4, 256, 0, stream>>>(ftb, ex4, offs, csr, out, M);
}

// Round 4
// 352.091 us; speedup vs baseline: 1.7117x; 1.0834x over previous
//
#include <hip/hip_runtime.h>

#define HEADS 4
#define DH 64
#define NHID 256   // HEADS*DH
#define KIN 256
#define NEG_SLOPE 0.2f

typedef __attribute__((ext_vector_type(8))) short short8;
typedef __attribute__((ext_vector_type(4))) float f32x4;

__device__ inline float bf2f(unsigned short u) {
  union { unsigned int i; float f; } v; v.i = ((unsigned int)u) << 16; return v.f;
}
__device__ inline unsigned short f2bf(float f) {
  union { float f; unsigned int i; } v; v.f = f;
  unsigned int r = v.i + 0x7FFF + ((v.i >> 16) & 1);  // RNE
  return (unsigned short)(r >> 16);
}

// -------- k_cvtW: W[k][n] fp32 -> Wt[n][k] bf16 (transpose+convert, tiny)
__global__ void k_cvtW(const float* __restrict__ W, unsigned short* __restrict__ Wt) {
  int n = blockIdx.x, k = threadIdx.x;
  Wt[n * 256 + k] = f2bf(W[k * 256 + n]);
}

// -------- k_gemm: fused projection + logits (unchanged from round 3)
__global__ __launch_bounds__(256, 2) void k_gemm(
    const float* __restrict__ feat, const unsigned short* __restrict__ Wt,
    const float* __restrict__ al, const float* __restrict__ ar,
    unsigned short* __restrict__ ftb, float* __restrict__ el,
    float* __restrict__ er, int M)
{
  __shared__ unsigned short As[64 * 32];    // 4 KB
  __shared__ unsigned short Bs[256 * 32];   // 16 KB
  const int t = threadIdx.x;
  const int lane = t & 63;
  const int w = t >> 6;                 // wave index == head == col-block
  const int row0 = blockIdx.x * 64;

  f32x4 acc[4][4] = {};

  const int ra = t >> 2, ca = t & 3;
  const int arow = min(row0 + ra, M - 1);
  const int adst = ra * 64 + (ca ^ ((ra >> 1) & 3)) * 16;   // swizzled LDS byte

  for (int k0 = 0; k0 < KIN; k0 += 32) {
    const float* ga = feat + (size_t)arow * KIN + k0 + ca * 8;
    float4 v0 = *(const float4*)ga;
    float4 v1 = *(const float4*)(ga + 4);
    short8 pk;
    pk[0] = (short)f2bf(v0.x); pk[1] = (short)f2bf(v0.y);
    pk[2] = (short)f2bf(v0.z); pk[3] = (short)f2bf(v0.w);
    pk[4] = (short)f2bf(v1.x); pk[5] = (short)f2bf(v1.y);
    pk[6] = (short)f2bf(v1.z); pk[7] = (short)f2bf(v1.w);
    *(short8*)((char*)As + adst) = pk;
    #pragma unroll
    for (int j = 0; j < 4; ++j) {
      int n = j * 64 + (t >> 2);
      int c = t & 3;
      const unsigned short* gb = Wt + n * 256 + k0 + ((c ^ ((n >> 1) & 3)) * 8);
      __builtin_amdgcn_global_load_lds(
          (const __attribute__((address_space(1))) void*)gb,
          (__attribute__((address_space(3))) void*)((char*)Bs + j * 4096 + t * 16),
          16, 0, 0);
    }
    __syncthreads();
    const int i = lane & 15, kc = lane >> 4;
    short8 af[4], bf[4];
    #pragma unroll
    for (int m = 0; m < 4; ++m) {
      int r = m * 16 + i;
      af[m] = *(const short8*)((const char*)As + r * 64 + ((kc ^ ((r >> 1) & 3)) * 16));
    }
    #pragma unroll
    for (int n = 0; n < 4; ++n) {
      int nr = w * 64 + n * 16 + i;
      bf[n] = *(const short8*)((const char*)Bs + nr * 64 + ((kc ^ ((nr >> 1) & 3)) * 16));
    }
    #pragma unroll
    for (int m = 0; m < 4; ++m)
      #pragma unroll
      for (int n = 0; n < 4; ++n)
        acc[m][n] = __builtin_amdgcn_mfma_f32_16x16x32_bf16(af[m], bf[n], acc[m][n], 0, 0, 0);
    __syncthreads();
  }

  const int ci = lane & 15, rg = lane >> 4;
  #pragma unroll
  for (int m = 0; m < 4; ++m) {
    #pragma unroll
    for (int r = 0; r < 4; ++r) {
      int grow = row0 + m * 16 + rg * 4 + r;
      if (grow < M) {
        unsigned short* fp = ftb + (size_t)grow * NHID + w * 64;
        #pragma unroll
        for (int n = 0; n < 4; ++n) fp[n * 16 + ci] = f2bf(acc[m][n][r]);
      }
    }
  }
  float alv[4], arv[4];
  #pragma unroll
  for (int n = 0; n < 4; ++n) {
    alv[n] = al[w * DH + n * 16 + ci];
    arv[n] = ar[w * DH + n * 16 + ci];
  }
  #pragma unroll
  for (int m = 0; m < 4; ++m) {
    #pragma unroll
    for (int r = 0; r < 4; ++r) {
      float pl = 0.f, pr = 0.f;
      #pragma unroll
      for (int n = 0; n < 4; ++n) {
        pl += acc[m][n][r] * alv[n];
        pr += acc[m][n][r] * arv[n];
      }
      pl += __shfl_xor(pl, 1); pl += __shfl_xor(pl, 2);
      pl += __shfl_xor(pl, 4); pl += __shfl_xor(pl, 8);
      pr += __shfl_xor(pr, 1); pr += __shfl_xor(pr, 2);
      pr += __shfl_xor(pr, 4); pr += __shfl_xor(pr, 8);
      if (ci == 0) {
        int grow = row0 + m * 16 + rg * 4 + r;
        if (grow < M) { el[grow * HEADS + w] = pl; er[grow * HEADS + w] = pr; }
      }
    }
  }
}

// ---------------- CSR build ----------------
__global__ void k_deg(const int* __restrict__ dst, int* __restrict__ deg, int E) {
  int e = blockIdx.x * 256 + threadIdx.x;
  if (e < E) atomicAdd(&deg[dst[e]], 1);
}

__global__ __launch_bounds__(1024) void k_scan1(const int* __restrict__ deg,
                                                int* __restrict__ offs,
                                                int* __restrict__ part, int N) {
  __shared__ int s[1024];
  int tid = threadIdx.x;
  int idx = blockIdx.x * 1024 + tid;
  int v = (idx < N) ? deg[idx] : 0;
  s[tid] = v;
  __syncthreads();
  for (int off = 1; off < 1024; off <<= 1) {
    int tmp = (tid >= off) ? s[tid - off] : 0;
    __syncthreads();
    s[tid] += tmp;
    __syncthreads();
  }
  if (idx < N) offs[idx] = s[tid] - v;
  if (tid == 1023) part[blockIdx.x] = s[1023];
}

__global__ __launch_bounds__(128) void k_scan2(const int* __restrict__ part,
                                               int* __restrict__ pbase, int nb) {
  __shared__ int s[128];
  int tid = threadIdx.x;
  int v = (tid < nb) ? part[tid] : 0;
  s[tid] = v;
  __syncthreads();
  for (int off = 1; off < 128; off <<= 1) {
    int tmp = (tid >= off) ? s[tid - off] : 0;
    __syncthreads();
    s[tid] += tmp;
    __syncthreads();
  }
  if (tid < nb) pbase[tid] = s[tid] - v;
}

__global__ void k_scan3(int* __restrict__ offs, const int* __restrict__ pbase,
                        int N, int E) {
  int idx = blockIdx.x * 256 + threadIdx.x;
  if (idx < N) offs[idx] += pbase[idx >> 10];
  if (idx == N) offs[N] = E;
}

// -------- k_fill: minimal scatter (atomic slot + 4B csr write)
__global__ void k_fill(const int* __restrict__ src, const int* __restrict__ dst,
                       const int* __restrict__ offs, int* __restrict__ cursor,
                       int* __restrict__ csr, int E) {
  int e = blockIdx.x * 256 + threadIdx.x;
  if (e < E) {
    int d = dst[e];
    int p = atomicAdd(&cursor[d], 1);
    csr[offs[d] + p] = src[e];
  }
}

// ---------------- Aggregation: wave per node, half-wave per edge, inline ex ----------------
// lanes 0-31 even edges, 32-63 odd edges; lane owns 8 dims (ushort8 = 16B).
// Software-pipelined: next csr+el gather issued before current FMA block.
__global__ __launch_bounds__(256) void k_aggr(
    const unsigned short* __restrict__ ftb, const float* __restrict__ el,
    const float* __restrict__ er, const int* __restrict__ offs,
    const int* __restrict__ csr, float* __restrict__ out, int N)
{
  int n = blockIdx.x * 4 + (threadIdx.x >> 6);
  int lane = threadIdx.x & 63;
  if (n >= N) return;
  int hl = lane & 31;          // dims hl*8 .. hl*8+7
  int half = lane >> 5;
  int hh = hl >> 3;            // head of my 8 dims
  int start = offs[n], end = offs[n + 1];
  const short8* ft8 = (const short8*)ftb;
  float acc[8] = {};
  float ws = 0.f;
  if (end > start) {
    float erh = er[n * HEADS + hh];
    // prologue: prefetch first edge for this half
    int e = start + half;
    bool v = e < end;
    int s = csr[v ? e : end - 1];
    float lx = el[s * 4 + hh];
    #pragma unroll 2
    for (int e0 = start; e0 < end; e0 += 2) {
      int cs = s; bool cv = v; float clx = lx;
      int en = e0 + 2 + half;
      v = en < end;
      if (v) { s = csr[en]; lx = el[s * 4 + hh]; }
      short8 f = ft8[(size_t)cs * 32 + hl];
      float x = clx + erh;
      x = x > 0.f ? x : NEG_SLOPE * x;
      float ex = cv ? __expf(x) : 0.f;
      ws += ex;
      #pragma unroll
      for (int j = 0; j < 8; ++j) acc[j] += ex * bf2f((unsigned short)f[j]);
    }
  }
  ws += __shfl_xor(ws, 32);
  #pragma unroll
  for (int j = 0; j < 8; ++j) acc[j] += __shfl_xor(acc[j], 32);
  if (half == 0) {
    float inv = (end > start) ? 1.f / ws : 0.f;
    float4* op = (float4*)(out + (size_t)n * NHID + hl * 8);
    op[0] = make_float4(acc[0] * inv, acc[1] * inv, acc[2] * inv, acc[3] * inv);
    op[1] = make_float4(acc[4] * inv, acc[5] * inv, acc[6] * inv, acc[7] * inv);
  }
}

// ---------------- launch ----------------
extern "C" void kernel_launch(void* const* d_in, const int* in_sizes, int n_in,
                              void* d_out, int out_size, void* d_ws, size_t ws_size,
                              hipStream_t stream)
{
  const float* feat = (const float*)d_in[0];
  const float* W    = (const float*)d_in[1];
  const float* al   = (const float*)d_in[2];
  const float* ar   = (const float*)d_in[3];
  const int*   src  = (const int*)d_in[4];
  const int*   dst  = (const int*)d_in[5];
  const int M = in_sizes[0] / KIN;   // 100000
  const int E = in_sizes[4];         // 1600000
  float* out = (float*)d_out;

  char* base = (char*)d_ws;
  size_t off = 0;
  auto alloc = [&](size_t b) { char* p = base + off; off = (off + b + 255) & ~(size_t)255; return p; };
  unsigned short* ftb = (unsigned short*)alloc((size_t)M * NHID * sizeof(unsigned short)); // 51.2 MB
  unsigned short* Wt  = (unsigned short*)alloc(256 * 256 * sizeof(unsigned short));
  float* el     = (float*)alloc((size_t)M * HEADS * sizeof(float));
  float* er     = (float*)alloc((size_t)M * HEADS * sizeof(float));
  int*   deg    = (int*)alloc((size_t)M * sizeof(int));
  int*   offs   = (int*)alloc((size_t)(M + 1) * sizeof(int));
  int*   cursor = (int*)alloc((size_t)M * sizeof(int));
  int*   part   = (int*)alloc(1024 * sizeof(int));
  int*   pbase  = (int*)alloc(1024 * sizeof(int));
  int*   csr    = (int*)alloc((size_t)E * sizeof(int));
  (void)ws_size; (void)n_in; (void)out_size;

  hipMemsetAsync(deg, 0, (size_t)M * sizeof(int), stream);
  hipMemsetAsync(cursor, 0, (size_t)M * sizeof(int), stream);

  k_cvtW<<<256, 256, 0, stream>>>(W, Wt);
  k_deg<<<(E + 255) / 256, 256, 0, stream>>>(dst, deg, E);
  int nb = (M + 1023) / 1024;
  k_scan1<<<nb, 1024, 0, stream>>>(deg, offs, part, M);
  k_scan2<<<1, 128, 0, stream>>>(part, pbase, nb);
  k_scan3<<<(M + 1 + 255) / 256, 256, 0, stream>>>(offs, pbase, M, E);
  k_gemm<<<(M + 63) / 64, 256, 0, stream>>>(feat, Wt, al, ar, ftb, el, er, M);
  k_fill<<<(E + 255) / 256, 256, 0, stream>>>(src, dst, offs, cursor, csr, E);
  k_aggr<<<(M + 3) / 4, 256, 0, stream>>>(ftb, el, er, offs, csr, out, M);
}